// Round 5
// baseline (1640.516 us; speedup 1.0000x reference)
//
#include <hip/hip_runtime.h>

#define H_DIM 128
#define F_IN  384
#define W1_STRIDE 388   // +4 elem pad: B-frag reads land 4 lanes/start-bank (vs 16-way unpadded)
#define HS_STRIDE 136

typedef __bf16 v8bf __attribute__((ext_vector_type(8)));
typedef float  v4f  __attribute__((ext_vector_type(4)));

// order-preserving float <-> uint encoding for atomicMax
__device__ __forceinline__ unsigned enc_f32(float v) {
    unsigned u = __float_as_uint(v);
    return (u & 0x80000000u) ? ~u : (u | 0x80000000u);
}
__device__ __forceinline__ float dec_f32(unsigned e) {
    if (e == 0u) return 0.0f;  // untouched node -> 0 (matches reference where())
    unsigned u = (e & 0x80000000u) ? (e & 0x7fffffffu) : ~e;
    return __uint_as_float(u);
}

// W1 [F_IN][H] fp32 -> W1T [H][F_IN] bf16 ; W2 [H][H] fp32 -> W2T [H][H] bf16
__global__ __launch_bounds__(256) void wconvert(const float* __restrict__ W1,
                                                const float* __restrict__ W2,
                                                __bf16* __restrict__ W1T,
                                                __bf16* __restrict__ W2T) {
    int i = blockIdx.x * 256 + threadIdx.x;
    if (i < F_IN * H_DIM) {
        int col = i / F_IN, k = i % F_IN;
        W1T[i] = (__bf16)W1[k * H_DIM + col];
    } else if (i < F_IN * H_DIM + H_DIM * H_DIM) {
        int j = i - F_IN * H_DIM;
        int col = j / H_DIM, k = j % H_DIM;
        W2T[j] = (__bf16)W2[k * H_DIM + col];
    }
}

// Persistent blocks: grid=256 (1 block/CU via 134KB LDS), 512 threads = 8 waves.
// W1T staged to LDS ONCE; then grid-stride over 128-edge tiles with ZERO
// __syncthreads in the loop (hs rows are wave-private; biases in regs; node-ids
// loaded directly). Each lane preloads all 12 leaf chunks -> deep HBM queue,
// no vmcnt(0) convoy.
__global__ __launch_bounds__(512, 2) void mlp_scatter(
    const float* __restrict__ leaf, const int* __restrict__ nidx,
    const __bf16* __restrict__ W1T, const __bf16* __restrict__ W2T,
    const float* __restrict__ b1, const float* __restrict__ b2,
    unsigned* __restrict__ agg, int E, int ntiles)
{
    __shared__ __bf16 w1s[128][W1_STRIDE];   // 99,328 B, resident all kernel
    __shared__ __bf16 hs[128][HS_STRIDE];    // 34,816 B, wave-private rows

    const int t  = threadIdx.x;
    const int w  = t >> 6;    // wave 0..7
    const int l  = t & 63;
    const int lr = l & 15;    // row/col within fragment
    const int lg = l >> 4;    // k-group

    // ---- stage W1T (96KB) into LDS once: thread t -> row t>>2, quarter (t&3)*96 ----
    {
        const int row = t >> 2;
        const int q   = (t & 3) * 96;
        const __bf16* src = W1T + row * F_IN + q;
#pragma unroll
        for (int i = 0; i < 12; ++i)
            *(v8bf*)&w1s[row][q + i * 8] = *(const v8bf*)(src + i * 8);
    }
    // per-lane biases in registers (L1-broadcast loads)
    float bb1[8], bb2[8];
#pragma unroll
    for (int f = 0; f < 8; ++f) { bb1[f] = b1[f * 16 + lr]; bb2[f] = b2[f * 16 + lr]; }
    __syncthreads();   // the only barrier in the kernel

    const int rb = w * 16 + lg * 4;
    const v4f vzero = {0.f, 0.f, 0.f, 0.f};

    for (int tile = blockIdx.x; tile < ntiles; tile += gridDim.x) {
        const long e0 = (long)tile * 128;
        long erow = e0 + w * 16 + lr;
        if (erow >= E) erow = E - 1;          // clamp; epilogue masks fake rows
        const float* arow = leaf + erow * (long)F_IN + lg * 8;

        // preload entire leaf row slice: 24 dwordx4 in flight per lane
        float4 L0[12], L1[12];
#pragma unroll
        for (int ks = 0; ks < 12; ++ks) {
            L0[ks] = *(const float4*)(arow + ks * 32);
            L1[ks] = *(const float4*)(arow + ks * 32 + 4);
        }
        int nd[4];
#pragma unroll
        for (int j = 0; j < 4; ++j) {
            const long ej = e0 + rb + j;
            nd[j] = (ej < E) ? nidx[ej] : -1;
        }

        // ---- layer 1: h = x @ W1, K=384, B-frags from resident LDS ----
        v4f acc[8];
#pragma unroll
        for (int f = 0; f < 8; ++f) acc[f] = vzero;
#pragma unroll
        for (int ks = 0; ks < 12; ++ks) {
            v8bf af;
            af[0] = (__bf16)L0[ks].x; af[1] = (__bf16)L0[ks].y;
            af[2] = (__bf16)L0[ks].z; af[3] = (__bf16)L0[ks].w;
            af[4] = (__bf16)L1[ks].x; af[5] = (__bf16)L1[ks].y;
            af[6] = (__bf16)L1[ks].z; af[7] = (__bf16)L1[ks].w;
#pragma unroll
            for (int f = 0; f < 8; ++f) {
                v8bf bfv = *(const v8bf*)&w1s[f * 16 + lr][ks * 32 + lg * 8];
                acc[f] = __builtin_amdgcn_mfma_f32_16x16x32_bf16(af, bfv, acc[f], 0, 0, 0);
            }
        }

        // ---- relu + bias -> bf16 hidden in LDS (wave-private rows) ----
#pragma unroll
        for (int f = 0; f < 8; ++f) {
#pragma unroll
            for (int j = 0; j < 4; ++j) {
                float v = fmaxf(acc[f][j] + bb1[f], 0.0f);
                hs[w * 16 + lg * 4 + j][f * 16 + lr] = (__bf16)v;
            }
        }

        // ---- layer 2: m = h @ W2, K=128; W2T frags from L1/L2 ----
        v4f acc2[8];
#pragma unroll
        for (int f = 0; f < 8; ++f) acc2[f] = vzero;
#pragma unroll
        for (int ks = 0; ks < 4; ++ks) {
            v8bf af2 = *(const v8bf*)&hs[w * 16 + lr][ks * 32 + lg * 8];
#pragma unroll
            for (int f = 0; f < 8; ++f) {
                v8bf bfv = *(const v8bf*)(W2T + (f * 16 + lr) * H_DIM + ks * 32 + lg * 8);
                acc2[f] = __builtin_amdgcn_mfma_f32_16x16x32_bf16(af2, bfv, acc2[f], 0, 0, 0);
            }
        }

        // ---- epilogue: + b2, fire-and-forget scatter-max ----
#pragma unroll
        for (int j = 0; j < 4; ++j) {
            if (nd[j] >= 0) {
                unsigned* dst = agg + (long)nd[j] * H_DIM + lr;
#pragma unroll
                for (int f = 0; f < 8; ++f)
                    atomicMax(dst + f * 16, enc_f32(acc2[f][j] + bb2[f]));
            }
        }
    }
}

// one wave per node row: lang = center + dec(agg); out = cos(gcn, lang)
__global__ __launch_bounds__(256) void cos_kernel(
    const float* __restrict__ center, const float* __restrict__ gcn,
    const unsigned* __restrict__ agg, float* __restrict__ out, int N)
{
    const int w = threadIdx.x >> 6, l = threadIdx.x & 63;
    const long row = (long)blockIdx.x * 4 + w;
    if (row >= N) return;
    const float2 g2 = *(const float2*)(gcn    + row * H_DIM + l * 2);
    const float2 c2 = *(const float2*)(center + row * H_DIM + l * 2);
    const uint2  e2 = *(const uint2*) (agg    + row * H_DIM + l * 2);
    const float l0 = c2.x + dec_f32(e2.x);
    const float l1 = c2.y + dec_f32(e2.y);
    float sgl = g2.x * l0 + g2.y * l1;
    float sgg = g2.x * g2.x + g2.y * g2.y;
    float sll = l0 * l0 + l1 * l1;
#pragma unroll
    for (int off = 32; off; off >>= 1) {
        sgl += __shfl_xor(sgl, off);
        sgg += __shfl_xor(sgg, off);
        sll += __shfl_xor(sll, off);
    }
    if (l == 0) {
        const float na = fmaxf(sqrtf(sgg), 1e-8f);
        const float nb = fmaxf(sqrtf(sll), 1e-8f);
        out[row] = sgl / (na * nb);
    }
}

extern "C" void kernel_launch(void* const* d_in, const int* in_sizes, int n_in,
                              void* d_out, int out_size, void* d_ws, size_t ws_size,
                              hipStream_t stream) {
    const float* center = (const float*)d_in[0];
    const float* leaf   = (const float*)d_in[1];
    const int*   nidx   = (const int*)  d_in[2];
    const float* gcn    = (const float*)d_in[3];
    const float* W1     = (const float*)d_in[4];
    const float* b1     = (const float*)d_in[5];
    const float* W2     = (const float*)d_in[6];
    const float* b2     = (const float*)d_in[7];

    const int E = in_sizes[2];             // 1,000,000
    const int N = in_sizes[0] / H_DIM;     // 65,536

    unsigned* agg = (unsigned*)d_ws;
    const size_t aggBytes = (size_t)N * H_DIM * sizeof(unsigned);
    __bf16* W1T = (__bf16*)((char*)d_ws + aggBytes);
    __bf16* W2T = W1T + (size_t)F_IN * H_DIM;

    const int ntiles = (E + 127) / 128;

    hipMemsetAsync(agg, 0, aggBytes, stream);
    wconvert<<<(F_IN * H_DIM + H_DIM * H_DIM + 255) / 256, 256, 0, stream>>>(W1, W2, W1T, W2T);
    mlp_scatter<<<256, 512, 0, stream>>>(leaf, nidx, W1T, W2T, b1, b2, agg, E, ntiles);
    cos_kernel<<<(N + 3) / 4, 256, 0, stream>>>(center, gcn, agg, (float*)d_out, N);
}